// Round 5
// baseline (9741.312 us; speedup 1.0000x reference)
//
#include <hip/hip_runtime.h>
#include <math.h>

// Fixed topology
#define BB 64
#define TT 512
#define II 256
#define HH 512
#define OO 256
#define MM 256
#define BT (BB*TT)

// ---- workspace layout (float offsets) ----
// UA  : (B,T,768) rows = [U1(512) | U0(256)] before step t, overwritten with
//       [v1_t(512) | mem_t(256)] during step t (consumed-then-overwritten).
// W1S : A1 swizzled for rnn phase 1 (H*M = 131072)
// W2R : [A2|A3] swizzled for rnn phase 2 (M*768 = 196608)
// WYS : y-weights [W12|Wm2] row-major (O*768 = 196608)
// c1, c2, c3
#define OFF_UA  0
#define OFF_W1S (BT*768)
#define OFF_W2R (OFF_W1S + HH*MM)
#define OFF_WYS (OFF_W2R + MM*768)
#define OFF_C1  (OFF_WYS + OO*768)
#define OFF_C2  (OFF_C1 + HH)
#define OFF_C3  (OFF_C2 + OO)
#define WS_FLOATS (OFF_C3 + MM)
// total 25,691,136 floats = 102.76 MB (same byte count as rounds 2-4, which passed)

// phase-1 weight swizzle: A1[h][k], h in [0,512), k in [0,256).
// thread tid=(q<<2)|ks owns h-pair {2q,2q+1} over k-slice [64ks, 64ks+64).
__device__ __forceinline__ int w1s_index(int h, int k) {
    int p = h >> 1, r = h & 1;
    int ks = k >> 6, rem = k & 63;
    int j = rem >> 2, e = rem & 3;
    int tid = (p << 2) | ks;
    return OFF_W1S + ((j*2 + r)*1024 + tid)*4 + e;
}
// phase-2 weight swizzle: A23[m][k], k in [0,768) = [A2(512) | A3(256)].
// thread tid=(m<<2)|ks owns output m over k-slice [192ks, 192ks+192).
__device__ __forceinline__ int w2r_index(int m, int k) {
    int ks = k / 192, jj = (k - 192*ks) >> 2, e = k & 3;
    int tid = (m << 2) | ks;
    return OFF_W2R + (jj*1024 + tid)*4 + e;
}

// c1 = W01@bm0 + b01 + bm1 ; c2 = b12+bm2 ; c3 = W0m@bm0 + W2m@c2 + b0m+b1m+b2m
__global__ void pre_vecs(const float* __restrict__ W01, const float* __restrict__ b01,
                         const float* __restrict__ b12, const float* __restrict__ bm0,
                         const float* __restrict__ bm1, const float* __restrict__ bm2,
                         const float* __restrict__ W0m, const float* __restrict__ b0m,
                         const float* __restrict__ b1m, const float* __restrict__ b2m,
                         const float* __restrict__ W2m, float* __restrict__ ws) {
    int id = blockIdx.x*256 + threadIdx.x;
    if (id < HH) {
        float acc = b01[id] + bm1[id];
        for (int i = 0; i < II; ++i) acc += W01[id*II + i] * bm0[i];
        ws[OFF_C1 + id] = acc;
    } else if (id < HH + OO) {
        int m = id - HH;
        ws[OFF_C2 + m] = b12[m] + bm2[m];
        float acc = b0m[m] + b1m[m] + b2m[m];
        for (int i = 0; i < II; ++i) acc += W0m[m*II + i] * bm0[i];
        for (int o = 0; o < OO; ++o) acc += W2m[m*OO + o] * (b12[o] + bm2[o]);
        ws[OFF_C3 + m] = acc;
    }
}

// A1 = W01@Wm0 + Wm1. grid 512 (h) x 256 (k)
__global__ void make_W1S(const float* __restrict__ W01, const float* __restrict__ Wm0,
                         const float* __restrict__ Wm1, float* __restrict__ ws) {
    int h = blockIdx.x, k = threadIdx.x;
    float acc = Wm1[h*MM + k];
    for (int i = 0; i < II; ++i) acc += W01[h*II + i] * Wm0[i*MM + k];
    ws[w1s_index(h, k)] = acc;
}
// A2 = W1m + W2m@W12. grid 256 (m) x 512 (k=h)
__global__ void make_A2(const float* __restrict__ W1m, const float* __restrict__ W2m,
                        const float* __restrict__ W12, float* __restrict__ ws) {
    int m = blockIdx.x, h = threadIdx.x;
    float acc = W1m[m*HH + h];
    for (int o = 0; o < OO; ++o) acc += W2m[m*OO + o] * W12[o*HH + h];
    ws[w2r_index(m, h)] = acc;
}
// A3 = W0m@Wm0 + W2m@Wm2. grid 256 (m) x 256 (m2): k = 512+m2
__global__ void make_A3(const float* __restrict__ W0m, const float* __restrict__ Wm0,
                        const float* __restrict__ W2m, const float* __restrict__ Wm2,
                        float* __restrict__ ws) {
    int m = blockIdx.x, m2 = threadIdx.x;
    float acc = 0.f;
    for (int i = 0; i < II; ++i) acc += W0m[m*II + i] * Wm0[i*MM + m2];
    for (int o = 0; o < OO; ++o) acc += W2m[m*OO + o] * Wm2[o*MM + m2];
    ws[w2r_index(m, 512 + m2)] = acc;
}
// WYS[o][768] = [W12 row | Wm2 row] plain row-major. grid 256 (o) x 768 (k)
__global__ void make_WYS(const float* __restrict__ W12, const float* __restrict__ Wm2,
                         float* __restrict__ ws) {
    int o = blockIdx.x, k = threadIdx.x;
    ws[OFF_WYS + o*768 + k] = (k < HH) ? W12[o*HH + k] : Wm2[o*MM + (k - HH)];
}

// ---- LDS-staged fp32 GEMM: out[n][c] = sum_k x[n][k]*W[c][k] + cvec[c] ----
// 128x128 tile, 256 threads, 8x8 per thread. K-chunk = 16.
// LDS row stride 22: w-reads (cx+16i)*22+k hit 16 distinct banks across cx
// (22*cx mod 32 all distinct for cx<16); a-reads broadcast across cx with 4
// distinct cy banks (0,22,12,2). float2 (b64) reads, conflict-free.
#define GS 22
template<int K>
__global__ __launch_bounds__(256)
void gemm_lds(const float* __restrict__ x, int ldx,
              const float* __restrict__ W, int ldw,
              const float* __restrict__ cvec,
              float* __restrict__ out, int ldo) {
    __shared__ float xs[128*GS];
    __shared__ float wsh[128*GS];
    const int tid = threadIdx.x;
    const int cx = tid & 15, cy = tid >> 4;
    const int n0 = blockIdx.x * 128;
    const int c0 = blockIdx.y * 128;
    const int lrow = tid >> 2;      // 0..63
    const int lk4 = tid & 3;
    float acc[8][8] = {};
    for (int k0 = 0; k0 < K; k0 += 16) {
        #pragma unroll
        for (int h = 0; h < 2; ++h) {
            int r = lrow + 64*h;
            float4 vx = *reinterpret_cast<const float4*>(&x[(size_t)(n0 + r)*ldx + k0 + 4*lk4]);
            float4 vw = *reinterpret_cast<const float4*>(&W[(size_t)(c0 + r)*ldw + k0 + 4*lk4]);
            int base = r*GS + 4*lk4;
            xs[base+0]=vx.x; xs[base+1]=vx.y; xs[base+2]=vx.z; xs[base+3]=vx.w;
            wsh[base+0]=vw.x; wsh[base+1]=vw.y; wsh[base+2]=vw.z; wsh[base+3]=vw.w;
        }
        __syncthreads();
        #pragma unroll
        for (int k = 0; k < 16; k += 2) {
            float2 a[8], w[8];
            #pragma unroll
            for (int j = 0; j < 8; ++j) a[j] = *reinterpret_cast<const float2*>(&xs[(cy + 16*j)*GS + k]);
            #pragma unroll
            for (int i = 0; i < 8; ++i) w[i] = *reinterpret_cast<const float2*>(&wsh[(cx + 16*i)*GS + k]);
            #pragma unroll
            for (int j = 0; j < 8; ++j)
                #pragma unroll
                for (int i = 0; i < 8; ++i)
                    acc[j][i] += a[j].x*w[i].x + a[j].y*w[i].y;
        }
        __syncthreads();
    }
    #pragma unroll
    for (int j = 0; j < 8; ++j) {
        int n = n0 + cy + 16*j;
        #pragma unroll
        for (int i = 0; i < 8; ++i) {
            int c = c0 + cx + 16*i;
            out[(size_t)n*ldo + c] = acc[j][i] + cvec[c];
        }
    }
}

__device__ __forceinline__ float dot4(float4 w, float4 a) {
    return w.x*a.x + w.y*a.y + w.z*a.z + w.w*a.w;
}

// ---- main persistent recurrent kernel ----
// grid = 64 (one block per batch row), 1024 threads (16 waves, 4/SIMD).
// thread tid: q=tid>>2 (output id), ks=tid&3 (k-slice id).
// Residency: phase-1 slots j=0..3 (both rows) in 32 VGPRs; phase-2 slots
// jj=0..8 in 144 KB LDS, jj=9..16 in 32 VGPRs; the rest streams from L2
// (880 KB/step, the per-CU L2-port-bound cost).
// y deferred: [v1|mem] written into the consumed UA row (write port).
// LDS act buf pad-swizzle: addr(k) = k + 4*(k>>6). Proven zero-conflict.
__global__ __launch_bounds__(1024, 4)
void rnn_main(float* __restrict__ ws, float* __restrict__ out) {
    __shared__ float buf[2][816];
    __shared__ float4 lds_w[9*1024];   // 144 KB of A23 (jj < 9)
    const int tid = threadIdx.x;
    const int b = blockIdx.x;
    const int q = tid >> 2;
    const int ks = tid & 3;
    const bool lead = (ks == 0);

    const float4* W1S4 = reinterpret_cast<const float4*>(ws + OFF_W1S);
    const float4* W2R4 = reinterpret_cast<const float4*>(ws + OFF_W2R);
    float* UAb = ws + OFF_UA + (size_t)b*TT*768;

    float4 w1e[4], w1o[4];             // A1 slots j=0..3: 32 VGPRs
    #pragma unroll
    for (int j = 0; j < 4; ++j) {
        w1e[j] = W1S4[(2*j)*1024 + tid];
        w1o[j] = W1S4[(2*j+1)*1024 + tid];
    }
    float4 w2reg[8];                   // A23 slots jj=9..16: 32 VGPRs
    #pragma unroll
    for (int i = 0; i < 8; ++i) w2reg[i] = W2R4[(9+i)*1024 + tid];
    #pragma unroll
    for (int j = 0; j < 9; ++j) lds_w[j*1024 + tid] = W2R4[j*1024 + tid];
    if (tid < 256) { int k = 512 + tid; buf[0][k + ((k>>6)<<2)] = 0.f; }
    __syncthreads();

    for (int t = 0; t < TT; ++t) {
        const int p = t & 1;
        const float4* bufp4 = reinterpret_cast<const float4*>(buf[p]);
        float* row = UAb + (size_t)t*768;

        // ---- phase 1: v1 = act(U1 + mem @ A1^T) ----
        float2 u1 = make_float2(0.f, 0.f);
        float u0 = 0.f;
        if (lead) {
            u1 = *reinterpret_cast<const float2*>(row + 2*q);
            u0 = row[512 + q];
        }
        float a0 = 0.f, a1 = 0.f;
        #pragma unroll
        for (int j = 0; j < 4; ++j) {                        // register-resident part
            float4 a = bufp4[136 + 17*ks + j];
            a0 += dot4(w1e[j], a);
            a1 += dot4(w1o[j], a);
        }
        #pragma unroll 4
        for (int j = 4; j < 16; ++j) {                       // streamed part
            float4 a  = bufp4[136 + 17*ks + j];
            float4 we = W1S4[(2*j)*1024 + tid];
            float4 wo = W1S4[(2*j+1)*1024 + tid];
            a0 += dot4(we, a);
            a1 += dot4(wo, a);
        }
        a0 += __shfl_xor(a0, 1); a0 += __shfl_xor(a0, 2);
        a1 += __shfl_xor(a1, 1); a1 += __shfl_xor(a1, 2);
        if (lead) {
            int h0 = 2*q;
            float v0 = a0 + u1.x, v1v = a1 + u1.y;
            if (h0 < 256) { v0 = fmaxf(v0, 0.f); v1v = fmaxf(v1v, 0.f); }  // wave-uniform
            else          { v0 = tanhf(v0);      v1v = tanhf(v1v); }
            int ai = h0 + ((h0>>6)<<2);
            *reinterpret_cast<float2*>(&buf[p][ai]) = make_float2(v0, v1v);
        }
        __syncthreads();

        // ---- phase 2: mem' = U0 + [v1|mem] @ A23^T ; store [v1|mem] for y ----
        float am = 0.f;
        #pragma unroll
        for (int jj = 0; jj < 9; ++jj) {                     // LDS-resident part
            float4 a = bufp4[51*ks + jj];
            am += dot4(lds_w[jj*1024 + tid], a);
        }
        #pragma unroll
        for (int i = 0; i < 8; ++i) {                        // register-resident part
            int jj = 9 + i;
            float4 a = bufp4[51*ks + jj + (jj>>4)];
            am += dot4(w2reg[i], a);
        }
        if (tid < 384) {                                     // act row -> UA (for y-GEMM)
            int k2 = 2*tid;
            float2 v = *reinterpret_cast<const float2*>(&buf[p][k2 + ((k2>>6)<<2)]);
            *reinterpret_cast<float2*>(row + k2) = v;
        }
        #pragma unroll 4
        for (int jj = 17; jj < 48; ++jj) {                   // streamed part
            float4 a = bufp4[51*ks + jj + (jj>>4)];
            am += dot4(W2R4[jj*1024 + tid], a);
        }
        am += __shfl_xor(am, 1); am += __shfl_xor(am, 2);
        if (lead) {
            float mv = am + u0;
            int k = 512 + q;
            buf[p^1][k + ((k>>6)<<2)] = mv;
            if (t == TT-1) out[(size_t)BT*OO + b*MM + q] = mv;
        }
        __syncthreads();
    }
}

extern "C" void kernel_launch(void* const* d_in, const int* in_sizes, int n_in,
                              void* d_out, int out_size, void* d_ws, size_t ws_size,
                              hipStream_t stream) {
    const float* inputs = (const float*)d_in[0];
    const float* W01 = (const float*)d_in[1];  const float* b01 = (const float*)d_in[2];
    const float* W12 = (const float*)d_in[3];  const float* b12 = (const float*)d_in[4];
    const float* Wm0 = (const float*)d_in[5];  const float* bm0 = (const float*)d_in[6];
    const float* Wm1 = (const float*)d_in[7];  const float* bm1 = (const float*)d_in[8];
    const float* Wm2 = (const float*)d_in[9];  const float* bm2 = (const float*)d_in[10];
    const float* W0m = (const float*)d_in[11]; const float* b0m = (const float*)d_in[12];
    const float* W1m = (const float*)d_in[13]; const float* b1m = (const float*)d_in[14];
    const float* W2m = (const float*)d_in[15]; const float* b2m = (const float*)d_in[16];
    float* outf = (float*)d_out;
    float* wsf = (float*)d_ws;

    // OOB guard (same byte count as rounds 2-4, which passed)
    if (ws_size < (size_t)WS_FLOATS * sizeof(float)) return;

    // fused-weight / bias precompute
    pre_vecs<<<3, 256, 0, stream>>>(W01, b01, b12, bm0, bm1, bm2, W0m, b0m, b1m, b2m, W2m, wsf);
    make_W1S<<<HH, 256, 0, stream>>>(W01, Wm0, Wm1, wsf);
    make_A2<<<MM, 512, 0, stream>>>(W1m, W2m, W12, wsf);
    make_A3<<<MM, 256, 0, stream>>>(W0m, Wm0, W2m, Wm2, wsf);
    make_WYS<<<OO, 768, 0, stream>>>(W12, Wm2, wsf);
    // input projections into UA rows: [U1(512) | U0(256)]
    gemm_lds<II><<<dim3(BT/128, HH/128), 256, 0, stream>>>(inputs, II, W01, II, wsf + OFF_C1, wsf + OFF_UA, 768);
    gemm_lds<II><<<dim3(BT/128, MM/128), 256, 0, stream>>>(inputs, II, W0m, II, wsf + OFF_C3, wsf + OFF_UA + 512, 768);
    // recurrent sweep (writes [v1|mem] back into UA rows)
    rnn_main<<<BB, 1024, 0, stream>>>(wsf, outf);
    // deferred y = [v1|mem] @ [W12|Wm2]^T + c2 over all (b,t)
    gemm_lds<768><<<dim3(BT/128, OO/128), 256, 0, stream>>>(wsf + OFF_UA, 768, wsf + OFF_WYS, 768, wsf + OFF_C2, outf, OO);
}